// Round 10
// baseline (273.891 us; speedup 1.0000x reference)
//
#include <hip/hip_runtime.h>

#define NRAYS 2048
#define NSAMP 128
#define HID   256

typedef __attribute__((ext_vector_type(8))) _Float16 half8;
typedef __attribute__((ext_vector_type(4))) float f32x4;

__device__ __forceinline__ unsigned pack2(_Float16 a, _Float16 b){
  unsigned short ua = __builtin_bit_cast(unsigned short, a);
  unsigned short ub = __builtin_bit_cast(unsigned short, b);
  return (unsigned)ua | ((unsigned)ub << 16);
}

// ---- weight preprocess: fp32 row-major [K][N] -> fp16 hi/lo packed [K/8][N][8], scaled x256
// half offsets in ws: W1hi 0, W1lo 65536, W2hi 131072, W2lo 196608,
//                     W3hi 262144 (padded N=16, 4096), W3lo 266240
__global__ void prep_kernel(const float* __restrict__ W1,
                            const float* __restrict__ W2,
                            const float* __restrict__ W3,
                            _Float16* __restrict__ out)
{
  int idx = blockIdx.x * 256 + threadIdx.x;
  float v; int pk, base, lstep;
  if (idx < 65536){
    int k = idx >> 8, n = idx & 255;
    v = W1[idx] * 256.f; pk = (((k >> 3) << 8) + n) * 8 + (k & 7); base = 0; lstep = 65536;
  } else if (idx < 131072){
    int j = idx - 65536; int k = j >> 8, n = j & 255;
    v = W2[j] * 256.f; pk = (((k >> 3) << 8) + n) * 8 + (k & 7); base = 131072; lstep = 65536;
  } else if (idx < 135168){
    int j = idx - 131072;
    int n = (j >> 3) & 15;
    int k = ((j >> 7) << 3) | (j & 7);
    v = (n < 4) ? W3[k * 4 + n] * 256.f : 0.f; pk = j; base = 262144; lstep = 4096;
  } else return;
  _Float16 hi = (_Float16)v;
  _Float16 lo = (_Float16)(v - (float)hi);
  out[base + pk] = hi;
  out[base + lstep + pk] = lo;
}

// Two 64-sample chunks per ray; LDS 70 KB. NO register cap: (256,1) lets the
// compiler allocate ~200 VGPR spill-free; runtime still fits 2 blocks/CU
// (VGPR <= 256 and 2x70KB <= 160KB LDS). (256,2)'s 128-cap caused ~330 MB/dispatch
// of scratch spill traffic (r8/r9 post-mortem).
__launch_bounds__(256, 1)
__global__ void nerf_kernel(const float* __restrict__ pos,
                            const float* __restrict__ tvals,
                            const float* __restrict__ W0,
                            const float* __restrict__ b0,
                            const float* __restrict__ b1,
                            const float* __restrict__ b2,
                            const float* __restrict__ b3,
                            const _Float16* __restrict__ wsu,
                            float* __restrict__ out)
{
  __shared__ __align__(16) _Float16 hbuf_hi[64 * HID]; // 32 KB swizzled
  __shared__ __align__(16) _Float16 hbuf_lo[64 * HID]; // 32 KB swizzled
  __shared__ float xls[NSAMP * 3];
  __shared__ float tl[NSAMP];
  __shared__ __align__(16) float obuf[NSAMP * 4];
  __shared__ float stot;
  __shared__ float redf[2][5];
  __shared__ int   redi[2];

  const int t    = threadIdx.x;
  const int ray  = blockIdx.x;
  const int lane = t & 63;
  const int wv   = t >> 6;     // wave id 0..3
  const int ln   = lane & 15;
  const int hi   = lane >> 4;
  const int swzx = (ln & 7) << 4;
  const float USC = 1.f / 65536.f;

  // ---- stage inputs
  {
    const float* pbase = pos + (size_t)ray * NSAMP * 3;
    xls[t] = pbase[t];
    if (t < NSAMP) xls[256 + t] = pbase[256 + t];
    if (t < NSAMP) tl[t] = tvals[(size_t)ray * NSAMP + t];
  }
  __syncthreads();

  const int c = (t & 127) << 1;   // two adjacent cols per thread (layer 0)

  for (int chunk = 0; chunk < 2; ++chunk){
    const int rbase = chunk << 6;

    // ---- layer 0: x(64x3) @ W0(3x256) + b0, relu -> hbuf hi/lo (x256, swizzled)
    {
      float wa0 = W0[c],       wb0 = W0[c + 1];
      float wa1 = W0[256 + c], wb1 = W0[256 + c + 1];
      float wa2 = W0[512 + c], wb2 = W0[512 + c + 1];
      float ba = b0[c], bb = b0[c + 1];
      int r0 = (t >> 7) << 5;    // rows 0..31 or 32..63 (local)
      for (int r = r0; r < r0 + 32; ++r){
        int gr = rbase + r;
        float x0 = xls[gr * 3 + 0], x1 = xls[gr * 3 + 1], x2 = xls[gr * 3 + 2];
        float ha = fmaxf(fmaf(x2, wa2, fmaf(x1, wa1, fmaf(x0, wa0, ba))), 0.f) * 256.f;
        float hb = fmaxf(fmaf(x2, wb2, fmaf(x1, wb1, fmaf(x0, wb0, bb))), 0.f) * 256.f;
        _Float16 ah = (_Float16)ha, bh = (_Float16)hb;
        _Float16 al = (_Float16)(ha - (float)ah), bl = (_Float16)(hb - (float)bh);
        int off = (r * 512 + c * 2) ^ ((r & 7) << 4);
        *(unsigned*)((char*)hbuf_hi + off) = pack2(ah, bh);
        *(unsigned*)((char*)hbuf_lo + off) = pack2(al, bl);
      }
    }
    __syncthreads();

    // ---- layers 1,2: h(64x256) @ W(256x256) + b, relu. fp16 split MFMA (3 per product)
    for (int L = 0; L < 2; ++L){
      const half8* Bh = (const half8*)(wsu + (L ? 131072 : 0));
      const half8* Bl = (const half8*)(wsu + (L ? 196608 : 65536));
      const float* bias = L ? b2 : b1;
      const int n0 = wv * 64;

      f32x4 acc[4][4];
      #pragma unroll
      for (int mb = 0; mb < 4; ++mb)
        #pragma unroll
        for (int nb = 0; nb < 4; ++nb)
          acc[mb][nb] = 0.f;

      #pragma unroll
      for (int kk = 0; kk < 8; ++kk){
        half8 Bhf[4], Blf[4];
        #pragma unroll
        for (int nb = 0; nb < 4; ++nb){
          int bi = (kk * 4 + hi) * 256 + n0 + nb * 16 + ln;
          Bhf[nb] = Bh[bi];
          Blf[nb] = Bl[bi];
        }
        #pragma unroll
        for (int mb = 0; mb < 4; ++mb){
          int row = mb * 16 + ln;
          int off = row * 512 + ((kk * 64 + hi * 16) ^ swzx);
          half8 Ahf = *(const half8*)((const char*)hbuf_hi + off);
          half8 Alf = *(const half8*)((const char*)hbuf_lo + off);
          #pragma unroll
          for (int nb = 0; nb < 4; ++nb){
            acc[mb][nb] = __builtin_amdgcn_mfma_f32_16x16x32_f16(Ahf, Bhf[nb], acc[mb][nb], 0, 0, 0);
            acc[mb][nb] = __builtin_amdgcn_mfma_f32_16x16x32_f16(Ahf, Blf[nb], acc[mb][nb], 0, 0, 0);
            acc[mb][nb] = __builtin_amdgcn_mfma_f32_16x16x32_f16(Alf, Bhf[nb], acc[mb][nb], 0, 0, 0);
          }
        }
      }

      float bv[4];
      #pragma unroll
      for (int nb = 0; nb < 4; ++nb) bv[nb] = bias[n0 + nb * 16 + ln];

      __syncthreads();   // all waves done reading hbuf before in-place overwrite
      #pragma unroll
      for (int mb = 0; mb < 4; ++mb){
        #pragma unroll
        for (int nb = 0; nb < 4; ++nb){
          int col = n0 + nb * 16 + ln;
          #pragma unroll
          for (int r = 0; r < 4; ++r){
            int row = mb * 16 + hi * 4 + r;
            float f = fmaxf(fmaf(acc[mb][nb][r], USC, bv[nb]), 0.f) * 256.f;
            _Float16 fh = (_Float16)f;
            _Float16 fl = (_Float16)(f - (float)fh);
            int off = (row * 512 + col * 2) ^ ((row & 7) << 4);
            *(_Float16*)((char*)hbuf_hi + off) = fh;
            *(_Float16*)((char*)hbuf_lo + off) = fl;
          }
        }
      }
      __syncthreads();
    }

    // ---- layer 3: h(64x256) @ W3(256x4) + b3 -> obuf f32 (N padded to 16)
    {
      const half8* B3h = (const half8*)(wsu + 262144);
      const half8* B3l = (const half8*)(wsu + 266240);
      f32x4 a3 = 0.f;
      #pragma unroll
      for (int kk = 0; kk < 8; ++kk){
        int bi = (kk * 4 + hi) * 16 + ln;
        half8 Bhf = B3h[bi];
        half8 Blf = B3l[bi];
        int row = wv * 16 + ln;
        int off = row * 512 + ((kk * 64 + hi * 16) ^ swzx);
        half8 Ah = *(const half8*)((const char*)hbuf_hi + off);
        half8 Al = *(const half8*)((const char*)hbuf_lo + off);
        a3 = __builtin_amdgcn_mfma_f32_16x16x32_f16(Ah, Bhf, a3, 0, 0, 0);
        a3 = __builtin_amdgcn_mfma_f32_16x16x32_f16(Ah, Blf, a3, 0, 0, 0);
        a3 = __builtin_amdgcn_mfma_f32_16x16x32_f16(Al, Bhf, a3, 0, 0, 0);
      }
      if (ln < 4){
        float b3v = b3[ln];
        #pragma unroll
        for (int r = 0; r < 4; ++r){
          int row = rbase + wv * 16 + hi * 4 + r;
          obuf[row * 4 + ln] = fmaf(a3[r], USC, b3v);
        }
      }
    }
    __syncthreads();   // L3 reads done before next chunk's layer-0 overwrites hbuf
  }

  // ---- epilogue: blend weights + outputs (threads 0..127 = waves 0,1)
  float inc = 1.f, alpha = 0.f, sig0 = 0.f, sig1 = 0.f, sig2 = 0.f;
  if (t < NSAMP){
    const float4* ov = (const float4*)obuf;
    float4 o = ov[t];
    sig0 = 1.f / (1.f + expf(-o.x));
    sig1 = 1.f / (1.f + expf(-o.y));
    sig2 = 1.f / (1.f + expf(-o.z));
    float op = (o.w > 20.f) ? o.w : log1pf(expf(o.w));
    float delta = (t < NSAMP - 1) ? (tl[t + 1] - tl[t]) : 1e10f;
    alpha = 1.f - expf(-op * delta);
    float u = fminf(1.f, 1.f - alpha + 1e-10f);
    inc = u;                               // inclusive product scan within wave
    #pragma unroll
    for (int off = 1; off < 64; off <<= 1){
      float v = __shfl_up(inc, off);
      if (lane >= off) inc *= v;
    }
    if (wv == 0 && lane == 63) stot = inc; // product of u[0..63]
  }
  __syncthreads();
  if (t < NSAMP){
    float ex = __shfl_up(inc, 1);
    if (lane == 0) ex = 1.f;
    if (wv == 1) ex *= stot;               // exclusive scan across waves
    float wgt = alpha * ex;
    float sr = wgt * sig0, sg = wgt * sig1, sb = wgt * sig2;
    float aw = (t < NSAMP - 1) ? wgt : 0.f;
    float wm = (t < NSAMP - 1) ? wgt : -1e30f;
    float wmv = wm;
    #pragma unroll
    for (int off = 32; off; off >>= 1){
      sr += __shfl_xor(sr, off);
      sg += __shfl_xor(sg, off);
      sb += __shfl_xor(sb, off);
      aw += __shfl_xor(aw, off);
      wm = fmaxf(wm, __shfl_xor(wm, off));
    }
    unsigned long long bal = __ballot(wmv == wm);
    int fi = __ffsll(bal) - 1;             // first max within wave
    if (lane == 0){
      redf[wv][0] = sr; redf[wv][1] = sg; redf[wv][2] = sb;
      redf[wv][3] = aw; redf[wv][4] = wm;
      redi[wv] = fi;
    }
  }
  __syncthreads();
  if (t == 0){
    float cr = redf[0][0] + redf[1][0];
    float cg = redf[0][1] + redf[1][1];
    float cb = redf[0][2] + redf[1][2];
    float asum = redf[0][3] + redf[1][3];
    int idx = (redf[1][4] > redf[0][4]) ? (64 + redi[1]) : redi[0]; // first max overall
    int cutoff = (asum < 0.1f) ? (NSAMP - 1) : idx;
    out[ray * 3 + 0] = cr;
    out[ray * 3 + 1] = cg;
    out[ray * 3 + 2] = cb;
    out[NRAYS * 3 + ray] = asum;
    out[NRAYS * 4 + ray] = tl[cutoff];
  }
}

extern "C" void kernel_launch(void* const* d_in, const int* in_sizes, int n_in,
                              void* d_out, int out_size, void* d_ws, size_t ws_size,
                              hipStream_t stream) {
  const float* pos = (const float*)d_in[0];
  const float* tv  = (const float*)d_in[1];
  const float* W0  = (const float*)d_in[2];
  const float* b0  = (const float*)d_in[3];
  const float* W1  = (const float*)d_in[4];
  const float* b1  = (const float*)d_in[5];
  const float* W2  = (const float*)d_in[6];
  const float* b2  = (const float*)d_in[7];
  const float* W3  = (const float*)d_in[8];
  const float* b3  = (const float*)d_in[9];
  _Float16* wsu = (_Float16*)d_ws;

  prep_kernel<<<528, 256, 0, stream>>>(W1, W2, W3, wsu);
  nerf_kernel<<<NRAYS, 256, 0, stream>>>(pos, tv, W0, b0, b1, b2, b3, wsu, (float*)d_out);
}

// Round 11
// 195.215 us; speedup vs baseline: 1.4030x; 1.4030x over previous
//
#include <hip/hip_runtime.h>

#define NRAYS 2048
#define NSAMP 128
#define HID   256

typedef __attribute__((ext_vector_type(8))) _Float16 half8;
typedef __attribute__((ext_vector_type(4))) float f32x4;

__device__ __forceinline__ unsigned pack2(_Float16 a, _Float16 b){
  unsigned short ua = __builtin_bit_cast(unsigned short, a);
  unsigned short ub = __builtin_bit_cast(unsigned short, b);
  return (unsigned)ua | ((unsigned)ub << 16);
}

// ---- weight preprocess: fp32 row-major [K][N] -> fp16 hi/lo packed [K/8][N][8], scaled x256
// half offsets in ws: W1hi 0, W1lo 65536, W2hi 131072, W2lo 196608,
//                     W3hi 262144 (padded N=16, 4096), W3lo 266240
__global__ void prep_kernel(const float* __restrict__ W1,
                            const float* __restrict__ W2,
                            const float* __restrict__ W3,
                            _Float16* __restrict__ out)
{
  int idx = blockIdx.x * 256 + threadIdx.x;
  float v; int pk, base, lstep;
  if (idx < 65536){
    int k = idx >> 8, n = idx & 255;
    v = W1[idx] * 256.f; pk = (((k >> 3) << 8) + n) * 8 + (k & 7); base = 0; lstep = 65536;
  } else if (idx < 131072){
    int j = idx - 65536; int k = j >> 8, n = j & 255;
    v = W2[j] * 256.f; pk = (((k >> 3) << 8) + n) * 8 + (k & 7); base = 131072; lstep = 65536;
  } else if (idx < 135168){
    int j = idx - 131072;
    int n = (j >> 3) & 15;
    int k = ((j >> 7) << 3) | (j & 7);
    v = (n < 4) ? W3[k * 4 + n] * 256.f : 0.f; pk = j; base = 262144; lstep = 4096;
  } else return;
  _Float16 hi = (_Float16)v;
  _Float16 lo = (_Float16)(v - (float)hi);
  out[base + pk] = hi;
  out[base + lstep + pk] = lo;
}

// Two 64-sample chunks per ray; LDS 70 KB -> 2 blocks/CU. (256,2) pins the
// 128-VGPR cap; K loops are RUNTIME loops (#pragma unroll 1) so B-fragment
// loads cannot be hoisted across kk (r9's spill cause: unrolled kk hoisted
// up to 256 regs of B loads). True live set ~120 regs -> no spill.
__launch_bounds__(256, 2)
__global__ void nerf_kernel(const float* __restrict__ pos,
                            const float* __restrict__ tvals,
                            const float* __restrict__ W0,
                            const float* __restrict__ b0,
                            const float* __restrict__ b1,
                            const float* __restrict__ b2,
                            const float* __restrict__ b3,
                            const _Float16* __restrict__ wsu,
                            float* __restrict__ out)
{
  __shared__ __align__(16) _Float16 hbuf_hi[64 * HID]; // 32 KB swizzled
  __shared__ __align__(16) _Float16 hbuf_lo[64 * HID]; // 32 KB swizzled
  __shared__ float xls[NSAMP * 3];
  __shared__ float tl[NSAMP];
  __shared__ __align__(16) float obuf[NSAMP * 4];
  __shared__ float stot;
  __shared__ float redf[2][5];
  __shared__ int   redi[2];

  const int t    = threadIdx.x;
  const int ray  = blockIdx.x;
  const int lane = t & 63;
  const int wv   = t >> 6;     // wave id 0..3
  const int ln   = lane & 15;
  const int hi   = lane >> 4;
  const int swzx = (ln & 7) << 4;
  const float USC = 1.f / 65536.f;

  // ---- stage inputs
  {
    const float* pbase = pos + (size_t)ray * NSAMP * 3;
    xls[t] = pbase[t];
    if (t < NSAMP) xls[256 + t] = pbase[256 + t];
    if (t < NSAMP) tl[t] = tvals[(size_t)ray * NSAMP + t];
  }
  __syncthreads();

  const int c = (t & 127) << 1;   // two adjacent cols per thread (layer 0)
  const int lnb = ln * 512;       // byte row base (row = mb*16+ln -> +mb*8192)

  for (int chunk = 0; chunk < 2; ++chunk){
    const int rbase = chunk << 6;

    // ---- layer 0: x(64x3) @ W0(3x256) + b0, relu -> hbuf hi/lo (x256, swizzled)
    {
      float wa0 = W0[c],       wb0 = W0[c + 1];
      float wa1 = W0[256 + c], wb1 = W0[256 + c + 1];
      float wa2 = W0[512 + c], wb2 = W0[512 + c + 1];
      float ba = b0[c], bb = b0[c + 1];
      int r0 = (t >> 7) << 5;    // rows 0..31 or 32..63 (local)
      for (int r = r0; r < r0 + 32; ++r){
        int gr = rbase + r;
        float x0 = xls[gr * 3 + 0], x1 = xls[gr * 3 + 1], x2 = xls[gr * 3 + 2];
        float ha = fmaxf(fmaf(x2, wa2, fmaf(x1, wa1, fmaf(x0, wa0, ba))), 0.f) * 256.f;
        float hb = fmaxf(fmaf(x2, wb2, fmaf(x1, wb1, fmaf(x0, wb0, bb))), 0.f) * 256.f;
        _Float16 ah = (_Float16)ha, bh = (_Float16)hb;
        _Float16 al = (_Float16)(ha - (float)ah), bl = (_Float16)(hb - (float)bh);
        int off = (r * 512 + c * 2) ^ ((r & 7) << 4);
        *(unsigned*)((char*)hbuf_hi + off) = pack2(ah, bh);
        *(unsigned*)((char*)hbuf_lo + off) = pack2(al, bl);
      }
    }
    __syncthreads();

    // ---- layers 1,2: h(64x256) @ W(256x256) + b, relu. fp16 split MFMA (3 per product)
    for (int L = 0; L < 2; ++L){
      const _Float16* Bhb = wsu + (L ? 131072 : 0);
      const _Float16* Blb = wsu + (L ? 196608 : 65536);
      const float* bias = L ? b2 : b1;
      const int n0 = wv * 64;

      f32x4 acc[4][4];
      #pragma unroll
      for (int mb = 0; mb < 4; ++mb)
        #pragma unroll
        for (int nb = 0; nb < 4; ++nb)
          acc[mb][nb] = 0.f;

      #pragma unroll 1            // RUNTIME loop: prevents B-load hoisting across kk
      for (int kk = 0; kk < 8; ++kk){
        const half8* Bhp = (const half8*)Bhb + (kk * 4 + hi) * 256 + n0 + ln;
        const half8* Blp = (const half8*)Blb + (kk * 4 + hi) * 256 + n0 + ln;
        half8 Bhf[4], Blf[4];
        #pragma unroll
        for (int nb = 0; nb < 4; ++nb){
          Bhf[nb] = Bhp[nb * 16];
          Blf[nb] = Blp[nb * 16];
        }
        int kx = lnb + ((kk * 64 + hi * 16) ^ swzx);
        #pragma unroll
        for (int mb = 0; mb < 4; ++mb){
          half8 Ahf = *(const half8*)((const char*)hbuf_hi + kx + mb * 8192);
          half8 Alf = *(const half8*)((const char*)hbuf_lo + kx + mb * 8192);
          #pragma unroll
          for (int nb = 0; nb < 4; ++nb)
            acc[mb][nb] = __builtin_amdgcn_mfma_f32_16x16x32_f16(Ahf, Bhf[nb], acc[mb][nb], 0, 0, 0);
          #pragma unroll
          for (int nb = 0; nb < 4; ++nb)
            acc[mb][nb] = __builtin_amdgcn_mfma_f32_16x16x32_f16(Ahf, Blf[nb], acc[mb][nb], 0, 0, 0);
          #pragma unroll
          for (int nb = 0; nb < 4; ++nb)
            acc[mb][nb] = __builtin_amdgcn_mfma_f32_16x16x32_f16(Alf, Bhf[nb], acc[mb][nb], 0, 0, 0);
        }
      }

      float bv[4];
      #pragma unroll
      for (int nb = 0; nb < 4; ++nb) bv[nb] = bias[n0 + nb * 16 + ln];

      __syncthreads();   // all waves done reading hbuf before in-place overwrite
      #pragma unroll
      for (int mb = 0; mb < 4; ++mb){
        #pragma unroll
        for (int nb = 0; nb < 4; ++nb){
          int col = n0 + nb * 16 + ln;
          #pragma unroll
          for (int r = 0; r < 4; ++r){
            int row = mb * 16 + hi * 4 + r;
            float f = fmaxf(fmaf(acc[mb][nb][r], USC, bv[nb]), 0.f) * 256.f;
            _Float16 fh = (_Float16)f;
            _Float16 fl = (_Float16)(f - (float)fh);
            int off = (row * 512 + col * 2) ^ ((row & 7) << 4);
            *(_Float16*)((char*)hbuf_hi + off) = fh;
            *(_Float16*)((char*)hbuf_lo + off) = fl;
          }
        }
      }
      __syncthreads();
    }

    // ---- layer 3: h(64x256) @ W3(256x4) + b3 -> obuf f32 (N padded to 16)
    {
      const _Float16* B3hb = wsu + 262144;
      const _Float16* B3lb = wsu + 266240;
      f32x4 a3 = 0.f;
      #pragma unroll 1            // runtime loop here too (r9: unrolled L3 hoisted ~128 regs)
      for (int kk = 0; kk < 8; ++kk){
        int bi = (kk * 4 + hi) * 16 + ln;
        half8 Bhf = ((const half8*)B3hb)[bi];
        half8 Blf = ((const half8*)B3lb)[bi];
        int kx = lnb + ((kk * 64 + hi * 16) ^ swzx) + wv * 8192;  // row = wv*16+ln
        half8 Ah = *(const half8*)((const char*)hbuf_hi + kx);
        half8 Al = *(const half8*)((const char*)hbuf_lo + kx);
        a3 = __builtin_amdgcn_mfma_f32_16x16x32_f16(Ah, Bhf, a3, 0, 0, 0);
        a3 = __builtin_amdgcn_mfma_f32_16x16x32_f16(Ah, Blf, a3, 0, 0, 0);
        a3 = __builtin_amdgcn_mfma_f32_16x16x32_f16(Al, Bhf, a3, 0, 0, 0);
      }
      if (ln < 4){
        float b3v = b3[ln];
        #pragma unroll
        for (int r = 0; r < 4; ++r){
          int row = rbase + wv * 16 + hi * 4 + r;
          obuf[row * 4 + ln] = fmaf(a3[r], USC, b3v);
        }
      }
    }
    __syncthreads();   // L3 reads done before next chunk's layer-0 overwrites hbuf
  }

  // ---- epilogue: blend weights + outputs (threads 0..127 = waves 0,1)
  float inc = 1.f, alpha = 0.f, sig0 = 0.f, sig1 = 0.f, sig2 = 0.f;
  if (t < NSAMP){
    const float4* ov = (const float4*)obuf;
    float4 o = ov[t];
    sig0 = 1.f / (1.f + expf(-o.x));
    sig1 = 1.f / (1.f + expf(-o.y));
    sig2 = 1.f / (1.f + expf(-o.z));
    float op = (o.w > 20.f) ? o.w : log1pf(expf(o.w));
    float delta = (t < NSAMP - 1) ? (tl[t + 1] - tl[t]) : 1e10f;
    alpha = 1.f - expf(-op * delta);
    float u = fminf(1.f, 1.f - alpha + 1e-10f);
    inc = u;                               // inclusive product scan within wave
    #pragma unroll
    for (int off = 1; off < 64; off <<= 1){
      float v = __shfl_up(inc, off);
      if (lane >= off) inc *= v;
    }
    if (wv == 0 && lane == 63) stot = inc; // product of u[0..63]
  }
  __syncthreads();
  if (t < NSAMP){
    float ex = __shfl_up(inc, 1);
    if (lane == 0) ex = 1.f;
    if (wv == 1) ex *= stot;               // exclusive scan across waves
    float wgt = alpha * ex;
    float sr = wgt * sig0, sg = wgt * sig1, sb = wgt * sig2;
    float aw = (t < NSAMP - 1) ? wgt : 0.f;
    float wm = (t < NSAMP - 1) ? wgt : -1e30f;
    float wmv = wm;
    #pragma unroll
    for (int off = 32; off; off >>= 1){
      sr += __shfl_xor(sr, off);
      sg += __shfl_xor(sg, off);
      sb += __shfl_xor(sb, off);
      aw += __shfl_xor(aw, off);
      wm = fmaxf(wm, __shfl_xor(wm, off));
    }
    unsigned long long bal = __ballot(wmv == wm);
    int fi = __ffsll(bal) - 1;             // first max within wave
    if (lane == 0){
      redf[wv][0] = sr; redf[wv][1] = sg; redf[wv][2] = sb;
      redf[wv][3] = aw; redf[wv][4] = wm;
      redi[wv] = fi;
    }
  }
  __syncthreads();
  if (t == 0){
    float cr = redf[0][0] + redf[1][0];
    float cg = redf[0][1] + redf[1][1];
    float cb = redf[0][2] + redf[1][2];
    float asum = redf[0][3] + redf[1][3];
    int idx = (redf[1][4] > redf[0][4]) ? (64 + redi[1]) : redi[0]; // first max overall
    int cutoff = (asum < 0.1f) ? (NSAMP - 1) : idx;
    out[ray * 3 + 0] = cr;
    out[ray * 3 + 1] = cg;
    out[ray * 3 + 2] = cb;
    out[NRAYS * 3 + ray] = asum;
    out[NRAYS * 4 + ray] = tl[cutoff];
  }
}

extern "C" void kernel_launch(void* const* d_in, const int* in_sizes, int n_in,
                              void* d_out, int out_size, void* d_ws, size_t ws_size,
                              hipStream_t stream) {
  const float* pos = (const float*)d_in[0];
  const float* tv  = (const float*)d_in[1];
  const float* W0  = (const float*)d_in[2];
  const float* b0  = (const float*)d_in[3];
  const float* W1  = (const float*)d_in[4];
  const float* b1  = (const float*)d_in[5];
  const float* W2  = (const float*)d_in[6];
  const float* b2  = (const float*)d_in[7];
  const float* W3  = (const float*)d_in[8];
  const float* b3  = (const float*)d_in[9];
  _Float16* wsu = (_Float16*)d_ws;

  prep_kernel<<<528, 256, 0, stream>>>(W1, W2, W3, wsu);
  nerf_kernel<<<NRAYS, 256, 0, stream>>>(pos, tv, W0, b0, b1, b2, b3, wsu, (float*)d_out);
}